// Round 6
// baseline (3627.480 us; speedup 1.0000x reference)
//
#include <hip/hip_runtime.h>
#include <cmath>

typedef __bf16 bf16x8 __attribute__((ext_vector_type(8)));
typedef float floatx4 __attribute__((ext_vector_type(4)));
typedef unsigned short u16;

#define B_ 16
#define T_ 512
#define D_ 512
#define H_ 1024
#define G_ 2048  // 2H
#define BH (B_ * H_)

// ---------------- cast fp32 -> bf16 (RNE) ----------------
__global__ void cast_f32_bf16(const float* __restrict__ src, u16* __restrict__ dst, int n) {
  int i = blockIdx.x * blockDim.x + threadIdx.x;
  int stride = gridDim.x * blockDim.x;
  for (; i < n; i += stride) {
    __bf16 b = (__bf16)src[i];
    dst[i] = *reinterpret_cast<u16*>(&b);
  }
}

// ---------------- w = x @ W^T  (bf16 MFMA, fp32 out), layout w[t][b][2H] ----------------
__launch_bounds__(256, 1)
__global__ void gemm_xW(const u16* __restrict__ xb, const u16* __restrict__ Wb,
                        float* __restrict__ w) {
  const int lane = threadIdx.x & 63;
  const int wv = threadIdx.x >> 6;
  const int rt0 = blockIdx.x * 16;          // rows r = b*T + t, 16 consecutive, same b
  const int bidx = rt0 >> 9;                // batch index (T=512)
  const int t0 = rt0 & 511;                 // base t for m=0
  const int am = lane & 15;
  const int kq = lane >> 4;

  bf16x8 af[16];
  {
    const u16* xrow = xb + (size_t)(rt0 + am) * D_ + kq * 8;
#pragma unroll
    for (int kk = 0; kk < 16; ++kk)
      af[kk] = *reinterpret_cast<const bf16x8*>(xrow + kk * 32);
  }

#pragma unroll 1
  for (int nt = 0; nt < 32; ++nt) {
    const int n0 = wv * 512 + nt * 16;
    floatx4 acc = {0.f, 0.f, 0.f, 0.f};
    const u16* wrow = Wb + (size_t)(n0 + am) * D_ + kq * 8;
#pragma unroll
    for (int kk = 0; kk < 16; ++kk) {
      bf16x8 bfr = *reinterpret_cast<const bf16x8*>(wrow + kk * 32);
      acc = __builtin_amdgcn_mfma_f32_16x16x32_bf16(af[kk], bfr, acc, 0, 0, 0);
    }
#pragma unroll
    for (int i = 0; i < 4; ++i) {
      int m = kq * 4 + i;
      w[(size_t)((t0 + m) * 16 + bidx) * G_ + n0 + am] = acc[i];
    }
  }
}

// ---------------- in-place LayerNorm over rows of 2048 ----------------
__launch_bounds__(256, 1)
__global__ void layernorm_rows(float* __restrict__ w, const float* __restrict__ gamma,
                               const float* __restrict__ beta) {
  float* r = w + (size_t)blockIdx.x * G_;
  float v[8];
  float s = 0.f, ss = 0.f;
#pragma unroll
  for (int i = 0; i < 8; ++i) {
    v[i] = r[threadIdx.x + i * 256];
    s += v[i];
    ss += v[i] * v[i];
  }
#pragma unroll
  for (int d = 1; d < 64; d <<= 1) {
    s += __shfl_xor(s, d, 64);
    ss += __shfl_xor(ss, d, 64);
  }
  __shared__ float ls[4], lss[4];
  const int wv = threadIdx.x >> 6;
  if ((threadIdx.x & 63) == 0) { ls[wv] = s; lss[wv] = ss; }
  __syncthreads();
  float S = ls[0] + ls[1] + ls[2] + ls[3];
  float SS = lss[0] + lss[1] + lss[2] + lss[3];
  float mu = S * (1.f / 2048.f);
  float var = SS * (1.f / 2048.f) - mu * mu;
  float rs = rsqrtf(var + 1e-5f);
#pragma unroll
  for (int i = 0; i < 8; ++i) {
    int g = threadIdx.x + i * 256;
    r[g] = (v[i] - mu) * rs * gamma[g] + beta[g];
  }
}

// ---------------- persistent LiGRU scan: register-resident, 1 barrier/step ----------------
// 32 blocks x 256 thr, ZERO LDS. Wave wv of block blk owns h cols
// [blk*32 + 8*wv, +8). Its MFMA B-tile columns are [a-rows j..j+7, z-rows H+j..H+j+7],
// so a/z pairing is a __shfl_xor(8); h state lives in 4 VGPRs/lane.
// Sync: plain h stores -> __syncthreads (vmcnt drain) -> RELEASE flag store (wbl2);
// consumers RELAXED-poll 32 flags, then ONE acquire fence (buffer_inv), plain loads.
__launch_bounds__(256, 1)
__global__ void ligru_scan(const float* __restrict__ w, const u16* __restrict__ Ub,
                           const float* __restrict__ h0, float* __restrict__ out,
                           u16* __restrict__ hbuf, unsigned* __restrict__ flags) {
  const int tid = threadIdx.x;
  const int lane = tid & 63;
  const int wv = tid >> 6;
  const int am = lane & 15;
  const int kq = lane >> 4;
  const int blk = blockIdx.x;
  const int j0 = blk * 32;
  const int col = j0 + 8 * wv + (am & 7);            // owned h column
  const int grow = (am < 8) ? col : (H_ + col);      // gate row mapped to B-col am

  // preload U fragments for this wave's mixed a/z tile: 16 rows x K=1024
  bf16x8 uf[32];
  {
    const u16* urow = Ub + (size_t)grow * H_ + kq * 8;
#pragma unroll
    for (int kk = 0; kk < 32; ++kk)
      uf[kk] = *reinterpret_cast<const bf16x8*>(urow + kk * 32);
  }

  // preload w for t=0 (layout [T][B][G]); per-lane gather of its 4 (m, grow) entries
  float wreg[4];
#pragma unroll
  for (int i = 0; i < 4; ++i)
    wreg[i] = w[(size_t)(kq * 4 + i) * G_ + grow];

  // init h state: hreg[i] = h0[col] (broadcast over batch); publish slice to buf0
  float hreg[4];
  {
    float hv = h0[col];
#pragma unroll
    for (int i = 0; i < 4; ++i) hreg[i] = hv;
    if (am < 8) {
      __bf16 hb = (__bf16)hv;
      u16 bits = *reinterpret_cast<u16*>(&hb);
#pragma unroll
      for (int i = 0; i < 4; ++i)
        hbuf[(kq * 4 + i) * H_ + col] = bits;
    }
  }
  __syncthreads();  // drain init stores (vmcnt(0) per wave)
  if (tid == 0)
    __hip_atomic_store(&flags[blk * 16], 1u, __ATOMIC_RELEASE,
                       __HIP_MEMORY_SCOPE_AGENT);

  for (int t = 0; t < T_; ++t) {
    const u16* cur = hbuf + (t & 1) * BH;
    u16* nxt = hbuf + ((t + 1) & 1) * BH;
    const unsigned want = (unsigned)(t + 1);

    // ---- wait for all producers of h_t: RELAXED polls, no inv storm ----
    {
      unsigned cnt = 0;
      for (;;) {
        unsigned f = 0xFFFFFFFFu;
        if (lane < 32)
          f = __hip_atomic_load(&flags[lane * 16], __ATOMIC_RELAXED,
                                __HIP_MEMORY_SCOPE_AGENT);
        if (__ballot(f < want) == 0ull) break;
        if (++cnt > (1u << 22)) break;  // safety valve: wrong > hung
      }
    }
    __builtin_amdgcn_fence(__ATOMIC_ACQUIRE, "agent");  // one buffer_inv

    // ---- gates tile: D[m=batch][n=am] over K=1024, 4 ILP chains ----
    floatx4 acc0 = {0, 0, 0, 0}, acc1 = {0, 0, 0, 0};
    floatx4 acc2 = {0, 0, 0, 0}, acc3 = {0, 0, 0, 0};
    {
      const u16* hb = cur + am * H_ + kq * 8;
#pragma unroll
      for (int kk = 0; kk < 8; ++kk) {
        bf16x8 a0 = *reinterpret_cast<const bf16x8*>(hb + (kk + 0) * 32);
        bf16x8 a1 = *reinterpret_cast<const bf16x8*>(hb + (kk + 8) * 32);
        bf16x8 a2 = *reinterpret_cast<const bf16x8*>(hb + (kk + 16) * 32);
        bf16x8 a3 = *reinterpret_cast<const bf16x8*>(hb + (kk + 24) * 32);
        acc0 = __builtin_amdgcn_mfma_f32_16x16x32_bf16(a0, uf[kk + 0], acc0, 0, 0, 0);
        acc1 = __builtin_amdgcn_mfma_f32_16x16x32_bf16(a1, uf[kk + 8], acc1, 0, 0, 0);
        acc2 = __builtin_amdgcn_mfma_f32_16x16x32_bf16(a2, uf[kk + 16], acc2, 0, 0, 0);
        acc3 = __builtin_amdgcn_mfma_f32_16x16x32_bf16(a3, uf[kk + 24], acc3, 0, 0, 0);
      }
    }
    floatx4 acc = (acc0 + acc1) + (acc2 + acc3);

    // prefetch w for t+1 (registers survive the next inv)
    float wnext[4];
    {
      int tn = (t + 1 < T_) ? (t + 1) : t;
      const float* wt = w + (size_t)tn * B_ * G_;
#pragma unroll
      for (int i = 0; i < 4; ++i)
        wnext[i] = wt[(size_t)(kq * 4 + i) * G_ + grow];
    }

    // ---- in-register a/z pairing + h update + publish ----
    float hnv[4];
#pragma unroll
    for (int i = 0; i < 4; ++i) {
      float g = acc[i] + wreg[i];
      float go = __shfl_xor(g, 8, 64);
      float a = (am < 8) ? g : go;
      float z = (am < 8) ? go : g;
      float zs = 1.f / (1.f + __expf(-z));
      float hn = zs * hreg[i] + (1.f - zs) * fmaxf(a, 0.f);
      hreg[i] = hn;
      hnv[i] = hn;
      if (am < 8) {
        __bf16 hb16 = (__bf16)hn;
        nxt[(kq * 4 + i) * H_ + col] = *reinterpret_cast<u16*>(&hb16);
      }
    }
    __syncthreads();  // drain all waves' publish stores (vmcnt(0) before barrier)
    if (tid == 0)
      __hip_atomic_store(&flags[blk * 16], want + 1u, __ATOMIC_RELEASE,
                         __HIP_MEMORY_SCOPE_AGENT);

    // out stores: nontemporal (keep L2 clean), off the critical path
    if (am < 8) {
#pragma unroll
      for (int i = 0; i < 4; ++i)
        __builtin_nontemporal_store(
            hnv[i], &out[((size_t)(kq * 4 + i) * T_ + t) * H_ + col]);
    }

#pragma unroll
    for (int i = 0; i < 4; ++i) wreg[i] = wnext[i];
  }
}

// ---------------- host ----------------
extern "C" void kernel_launch(void* const* d_in, const int* in_sizes, int n_in,
                              void* d_out, int out_size, void* d_ws, size_t ws_size,
                              hipStream_t stream) {
  (void)in_sizes; (void)n_in; (void)out_size; (void)ws_size;
  const float* x = (const float*)d_in[0];
  const float* Ww = (const float*)d_in[1];
  const float* Uw = (const float*)d_in[2];
  const float* gamma = (const float*)d_in[3];
  const float* beta = (const float*)d_in[4];
  const float* h0 = (const float*)d_in[5];
  float* out = (float*)d_out;

  char* p = (char*)d_ws;
  u16* xb = (u16*)p;      p += (size_t)8192 * 512 * 2;   // 8 MB
  u16* Wb = (u16*)p;      p += (size_t)2048 * 512 * 2;   // 2 MB
  u16* Ub = (u16*)p;      p += (size_t)2048 * 1024 * 2;  // 4 MB
  float* w = (float*)p;   p += (size_t)8192 * 2048 * 4;  // 64 MB  [T][B][G]
  u16* hbuf = (u16*)p;    p += (size_t)2 * BH * 2;       // 64 KB (double buffer)
  unsigned* flags = (unsigned*)p; p += 32 * 64;          // 2 KB flag lines

  hipMemsetAsync(flags, 0, 32 * 64, stream);  // epochs start below 1
  cast_f32_bf16<<<512, 256, 0, stream>>>(x, xb, 8192 * 512);
  cast_f32_bf16<<<256, 256, 0, stream>>>(Ww, Wb, 2048 * 512);
  cast_f32_bf16<<<256, 256, 0, stream>>>(Uw, Uw ? Ub : Ub, 2048 * 1024);
  gemm_xW<<<512, 256, 0, stream>>>(xb, Wb, w);
  layernorm_rows<<<8192, 256, 0, stream>>>(w, gamma, beta);

  const float* wc = w;
  const u16* Ubc = Ub;
  void* args[6] = { (void*)&wc, (void*)&Ubc, (void*)&h0, (void*)&out,
                    (void*)&hbuf, (void*)&flags };
  hipLaunchCooperativeKernel((void*)ligru_scan, dim3(32), dim3(256), args, 0, stream);
}

// Round 8
// 3030.126 us; speedup vs baseline: 1.1971x; 1.1971x over previous
//
#include <hip/hip_runtime.h>
#include <hip/hip_cooperative_groups.h>
#include <cmath>

typedef __bf16 bf16x8 __attribute__((ext_vector_type(8)));
typedef float floatx4 __attribute__((ext_vector_type(4)));
typedef unsigned short u16;

#define B_ 16
#define T_ 512
#define D_ 512
#define H_ 1024
#define G_ 2048  // 2H
#define BH (B_ * H_)

#define AS_BF16X8(x) (*reinterpret_cast<bf16x8*>(&(x)))

// ---------------- cast fp32 -> bf16 (RNE) ----------------
__global__ void cast_f32_bf16(const float* __restrict__ src, u16* __restrict__ dst, int n) {
  int i = blockIdx.x * blockDim.x + threadIdx.x;
  int stride = gridDim.x * blockDim.x;
  for (; i < n; i += stride) {
    __bf16 b = (__bf16)src[i];
    dst[i] = *reinterpret_cast<u16*>(&b);
  }
}

// ---------------- w = x @ W^T  (bf16 MFMA, fp32 out), layout w[t][b][2H] ----------------
__launch_bounds__(256, 1)
__global__ void gemm_xW(const u16* __restrict__ xb, const u16* __restrict__ Wb,
                        float* __restrict__ w) {
  const int lane = threadIdx.x & 63;
  const int wv = threadIdx.x >> 6;
  const int rt0 = blockIdx.x * 16;
  const int bidx = rt0 >> 9;
  const int t0 = rt0 & 511;
  const int am = lane & 15;
  const int kq = lane >> 4;

  bf16x8 af[16];
  {
    const u16* xrow = xb + (size_t)(rt0 + am) * D_ + kq * 8;
#pragma unroll
    for (int kk = 0; kk < 16; ++kk)
      af[kk] = *reinterpret_cast<const bf16x8*>(xrow + kk * 32);
  }

#pragma unroll 1
  for (int nt = 0; nt < 32; ++nt) {
    const int n0 = wv * 512 + nt * 16;
    floatx4 acc = {0.f, 0.f, 0.f, 0.f};
    const u16* wrow = Wb + (size_t)(n0 + am) * D_ + kq * 8;
#pragma unroll
    for (int kk = 0; kk < 16; ++kk) {
      bf16x8 bfr = *reinterpret_cast<const bf16x8*>(wrow + kk * 32);
      acc = __builtin_amdgcn_mfma_f32_16x16x32_bf16(af[kk], bfr, acc, 0, 0, 0);
    }
#pragma unroll
    for (int i = 0; i < 4; ++i) {
      int m = kq * 4 + i;
      w[(size_t)((t0 + m) * 16 + bidx) * G_ + n0 + am] = acc[i];
    }
  }
}

// ---------------- in-place LayerNorm over rows of 2048 ----------------
__launch_bounds__(256, 1)
__global__ void layernorm_rows(float* __restrict__ w, const float* __restrict__ gamma,
                               const float* __restrict__ beta) {
  float* r = w + (size_t)blockIdx.x * G_;
  float v[8];
  float s = 0.f, ss = 0.f;
#pragma unroll
  for (int i = 0; i < 8; ++i) {
    v[i] = r[threadIdx.x + i * 256];
    s += v[i];
    ss += v[i] * v[i];
  }
#pragma unroll
  for (int d = 1; d < 64; d <<= 1) {
    s += __shfl_xor(s, d, 64);
    ss += __shfl_xor(ss, d, 64);
  }
  __shared__ float ls[4], lss[4];
  const int wv = threadIdx.x >> 6;
  if ((threadIdx.x & 63) == 0) { ls[wv] = s; lss[wv] = ss; }
  __syncthreads();
  float S = ls[0] + ls[1] + ls[2] + ls[3];
  float SS = lss[0] + lss[1] + lss[2] + lss[3];
  float mu = S * (1.f / 2048.f);
  float var = SS * (1.f / 2048.f) - mu * mu;
  float rs = rsqrtf(var + 1e-5f);
#pragma unroll
  for (int i = 0; i < 8; ++i) {
    int g = threadIdx.x + i * 256;
    r[g] = (v[i] - mu) * rs * gamma[g] + beta[g];
  }
}

// ---------------- persistent LiGRU scan: MALL-direct h/flag exchange ----------------
// 32 blocks x 512 thr. Block blk owns h cols [blk*32, +32). 8 waves:
// wave wv -> tile jt=wv>>1 (B-cols: am<8 -> a-row j0+8jt+am, am>=8 -> z-row
// H+j0+8jt+am-8), K-half kh=wv&1 (512 wide) so uf[16]=64 VGPRs stays resident.
// ALL shared data (h, flags) moves via sc0 sc1 (L1+L2 bypass) loads/stores —
// served coherently by the die-level Infinity Cache. No fences, no wbl2/inv.
// Producer: h stores (bypass, vmcnt0) -> __syncthreads -> flag store (bypass).
// Consumer: poll 32 flags (bypass loads) -> bundle of 16 bypass dwordx4 loads.
__launch_bounds__(512, 2)
__global__ void ligru_scan(const float* __restrict__ w, const u16* __restrict__ Ub,
                           const float* __restrict__ h0, float* __restrict__ out,
                           u16* __restrict__ hbuf, unsigned* __restrict__ flags) {
  const int tid = threadIdx.x;
  const int lane = tid & 63;
  const int wv = tid >> 6;
  const int am = lane & 15;
  const int kq = lane >> 4;
  const int blk = blockIdx.x;
  const int j0 = blk * 32;
  const int jt = wv >> 1;
  const int kh = wv & 1;

  __shared__ float lds_r[4][2][16][16];  // [tile][K-half][batch][B-col]

  const int grow = (am < 8) ? (j0 + 8 * jt + am) : (H_ + j0 + 8 * jt + (am - 8));

  // U fragments: 16 rows x K=512, register resident (64 VGPR)
  bf16x8 uf[16];
  {
    const u16* urow = Ub + (size_t)grow * H_ + kh * 512 + kq * 8;
#pragma unroll
    for (int kk = 0; kk < 16; ++kk)
      uf[kk] = *reinterpret_cast<const bf16x8*>(urow + kk * 32);
  }

  // per-thread h ownership: batch ub, col jj
  const int ub = tid >> 5;
  const int jj = tid & 31;
  const int col = j0 + jj;
  float hreg = h0[col];
  float wa = w[(size_t)ub * G_ + col];
  float wz = w[(size_t)ub * G_ + H_ + col];

  // publish h_0 slice: even lanes pack (jj, jj+1) into one dword, bypass store
  {
    __bf16 hb = (__bf16)hreg;
    unsigned v = *reinterpret_cast<u16*>(&hb);
    unsigned hi = __shfl_down(v, 1, 64);
    if ((jj & 1) == 0) {
      unsigned pk = (hi << 16) | v;
      unsigned* p = reinterpret_cast<unsigned*>(hbuf + ub * H_ + col);
      asm volatile("global_store_dword %0, %1, off sc0 sc1\n\ts_waitcnt vmcnt(0)"
                   :: "v"(p), "v"(pk) : "memory");
    }
  }
  __syncthreads();
  if (tid == 0) {
    unsigned one = 1u;
    unsigned* p = flags + blk * 16;
    asm volatile("global_store_dword %0, %1, off sc0 sc1\n\ts_waitcnt vmcnt(0)"
                 :: "v"(p), "v"(one) : "memory");
  }

  for (int t = 0; t < T_; ++t) {
    const u16* cur = hbuf + (t & 1) * BH;
    u16* nxt = hbuf + ((t + 1) & 1) * BH;
    const unsigned want = (unsigned)(t + 1);

    // ---- poll all 32 block flags via bypass loads (each read hits MALL) ----
    {
      const unsigned* fp = flags + (lane & 31) * 16;
      unsigned spins = 0;
      for (;;) {
        unsigned f = 0xFFFFFFFFu;
        if (lane < 32) {
          asm volatile("global_load_dword %0, %1, off sc0 sc1\n\ts_waitcnt vmcnt(0)"
                       : "=v"(f) : "v"(fp) : "memory");
        }
        if (__ballot(f < want) == 0ull) break;
        if (++spins > (1u << 13)) break;  // valve: wrong > hung
      }
    }

    // ---- h A-fragments: 16 bypass dwordx4 in one bundle (256 B/lane) ----
    floatx4 q0, q1, q2, q3, q4, q5, q6, q7, q8, q9, q10, q11, q12, q13, q14, q15;
    {
      const u16* hb = cur + am * H_ + kh * 512 + kq * 8;
      asm volatile(
          "global_load_dwordx4 %0, %16, off sc0 sc1\n\t"
          "global_load_dwordx4 %1, %16, off offset:64 sc0 sc1\n\t"
          "global_load_dwordx4 %2, %16, off offset:128 sc0 sc1\n\t"
          "global_load_dwordx4 %3, %16, off offset:192 sc0 sc1\n\t"
          "global_load_dwordx4 %4, %16, off offset:256 sc0 sc1\n\t"
          "global_load_dwordx4 %5, %16, off offset:320 sc0 sc1\n\t"
          "global_load_dwordx4 %6, %16, off offset:384 sc0 sc1\n\t"
          "global_load_dwordx4 %7, %16, off offset:448 sc0 sc1\n\t"
          "global_load_dwordx4 %8, %16, off offset:512 sc0 sc1\n\t"
          "global_load_dwordx4 %9, %16, off offset:576 sc0 sc1\n\t"
          "global_load_dwordx4 %10, %16, off offset:640 sc0 sc1\n\t"
          "global_load_dwordx4 %11, %16, off offset:704 sc0 sc1\n\t"
          "global_load_dwordx4 %12, %16, off offset:768 sc0 sc1\n\t"
          "global_load_dwordx4 %13, %16, off offset:832 sc0 sc1\n\t"
          "global_load_dwordx4 %14, %16, off offset:896 sc0 sc1\n\t"
          "global_load_dwordx4 %15, %16, off offset:960 sc0 sc1\n\t"
          "s_waitcnt vmcnt(0)"
          : "=&v"(q0), "=&v"(q1), "=&v"(q2), "=&v"(q3),
            "=&v"(q4), "=&v"(q5), "=&v"(q6), "=&v"(q7),
            "=&v"(q8), "=&v"(q9), "=&v"(q10), "=&v"(q11),
            "=&v"(q12), "=&v"(q13), "=&v"(q14), "=&v"(q15)
          : "v"(hb)
          : "memory");
    }

    // ---- 16 MFMAs over this wave's K-half, 2 ILP chains ----
    floatx4 acc0 = {0, 0, 0, 0}, acc1 = {0, 0, 0, 0};
    acc0 = __builtin_amdgcn_mfma_f32_16x16x32_bf16(AS_BF16X8(q0), uf[0], acc0, 0, 0, 0);
    acc1 = __builtin_amdgcn_mfma_f32_16x16x32_bf16(AS_BF16X8(q8), uf[8], acc1, 0, 0, 0);
    acc0 = __builtin_amdgcn_mfma_f32_16x16x32_bf16(AS_BF16X8(q1), uf[1], acc0, 0, 0, 0);
    acc1 = __builtin_amdgcn_mfma_f32_16x16x32_bf16(AS_BF16X8(q9), uf[9], acc1, 0, 0, 0);
    acc0 = __builtin_amdgcn_mfma_f32_16x16x32_bf16(AS_BF16X8(q2), uf[2], acc0, 0, 0, 0);
    acc1 = __builtin_amdgcn_mfma_f32_16x16x32_bf16(AS_BF16X8(q10), uf[10], acc1, 0, 0, 0);
    acc0 = __builtin_amdgcn_mfma_f32_16x16x32_bf16(AS_BF16X8(q3), uf[3], acc0, 0, 0, 0);
    acc1 = __builtin_amdgcn_mfma_f32_16x16x32_bf16(AS_BF16X8(q11), uf[11], acc1, 0, 0, 0);
    acc0 = __builtin_amdgcn_mfma_f32_16x16x32_bf16(AS_BF16X8(q4), uf[4], acc0, 0, 0, 0);
    acc1 = __builtin_amdgcn_mfma_f32_16x16x32_bf16(AS_BF16X8(q12), uf[12], acc1, 0, 0, 0);
    acc0 = __builtin_amdgcn_mfma_f32_16x16x32_bf16(AS_BF16X8(q5), uf[5], acc0, 0, 0, 0);
    acc1 = __builtin_amdgcn_mfma_f32_16x16x32_bf16(AS_BF16X8(q13), uf[13], acc1, 0, 0, 0);
    acc0 = __builtin_amdgcn_mfma_f32_16x16x32_bf16(AS_BF16X8(q6), uf[6], acc0, 0, 0, 0);
    acc1 = __builtin_amdgcn_mfma_f32_16x16x32_bf16(AS_BF16X8(q14), uf[14], acc1, 0, 0, 0);
    acc0 = __builtin_amdgcn_mfma_f32_16x16x32_bf16(AS_BF16X8(q7), uf[7], acc0, 0, 0, 0);
    acc1 = __builtin_amdgcn_mfma_f32_16x16x32_bf16(AS_BF16X8(q15), uf[15], acc1, 0, 0, 0);
    floatx4 acc = acc0 + acc1;

    // w prefetch for t+1 (plain cached loads, read-only data)
    float wan, wzn;
    {
      int tn = (t + 1 < T_) ? (t + 1) : t;
      const float* wt = w + (size_t)(tn * 16 + ub) * G_;
      wan = wt[col];
      wzn = wt[H_ + col];
    }

    // park partial gates for cross-wave reduce
#pragma unroll
    for (int i = 0; i < 4; ++i)
      lds_r[jt][kh][kq * 4 + i][am] = acc[i];
    __syncthreads();

    // ---- update: combine K-halves, pair a/z, publish via bypass store ----
    float hn;
    {
      const int tl = jj >> 3, c = jj & 7;
      float a = lds_r[tl][0][ub][c] + lds_r[tl][1][ub][c] + wa;
      float z = lds_r[tl][0][ub][8 + c] + lds_r[tl][1][ub][8 + c] + wz;
      float zs = 1.f / (1.f + __expf(-z));
      hn = zs * hreg + (1.f - zs) * fmaxf(a, 0.f);
      hreg = hn;
      __bf16 hb16 = (__bf16)hn;
      unsigned v = *reinterpret_cast<u16*>(&hb16);
      unsigned hi = __shfl_down(v, 1, 64);
      if ((jj & 1) == 0) {
        unsigned pk = (hi << 16) | v;
        unsigned* p = reinterpret_cast<unsigned*>(nxt + ub * H_ + col);
        asm volatile("global_store_dword %0, %1, off sc0 sc1\n\ts_waitcnt vmcnt(0)"
                     :: "v"(p), "v"(pk) : "memory");
      }
    }
    __syncthreads();  // all waves' h stores are at MALL; also guards lds_r reuse
    if (tid == 0) {
      unsigned nv = want + 1u;
      unsigned* p = flags + blk * 16;
      asm volatile("global_store_dword %0, %1, off sc0 sc1\n\ts_waitcnt vmcnt(0)"
                   :: "v"(p), "v"(nv) : "memory");
    }

    // out store off the critical path (plain nontemporal, never invalidated)
    __builtin_nontemporal_store(hn, &out[((size_t)ub * T_ + t) * H_ + col]);

    wa = wan; wz = wzn;
  }
}

// ---------------- host ----------------
extern "C" void kernel_launch(void* const* d_in, const int* in_sizes, int n_in,
                              void* d_out, int out_size, void* d_ws, size_t ws_size,
                              hipStream_t stream) {
  (void)in_sizes; (void)n_in; (void)out_size; (void)ws_size;
  const float* x = (const float*)d_in[0];
  const float* Ww = (const float*)d_in[1];
  const float* Uw = (const float*)d_in[2];
  const float* gamma = (const float*)d_in[3];
  const float* beta = (const float*)d_in[4];
  const float* h0 = (const float*)d_in[5];
  float* out = (float*)d_out;

  char* p = (char*)d_ws;
  u16* xb = (u16*)p;      p += (size_t)8192 * 512 * 2;   // 8 MB
  u16* Wb = (u16*)p;      p += (size_t)2048 * 512 * 2;   // 2 MB
  u16* Ub = (u16*)p;      p += (size_t)2048 * 1024 * 2;  // 4 MB
  float* w = (float*)p;   p += (size_t)8192 * 2048 * 4;  // 64 MB  [T][B][G]
  u16* hbuf = (u16*)p;    p += (size_t)2 * BH * 2;       // 64 KB (double buffer)
  unsigned* flags = (unsigned*)p; p += 32 * 64;          // 2 KB flag lines

  hipMemsetAsync(flags, 0, 32 * 64, stream);  // epochs start below 1
  cast_f32_bf16<<<512, 256, 0, stream>>>(x, xb, 8192 * 512);
  cast_f32_bf16<<<256, 256, 0, stream>>>(Ww, Wb, 2048 * 512);
  cast_f32_bf16<<<256, 256, 0, stream>>>(Uw, Ub, 2048 * 1024);
  gemm_xW<<<512, 256, 0, stream>>>(xb, Wb, w);
  layernorm_rows<<<8192, 256, 0, stream>>>(w, gamma, beta);

  const float* wc = w;
  const u16* Ubc = Ub;
  void* args[6] = { (void*)&wc, (void*)&Ubc, (void*)&h0, (void*)&out,
                    (void*)&hbuf, (void*)&flags };
  hipLaunchCooperativeKernel((void*)ligru_scan, dim3(32), dim3(512), args, 0, stream);
}

// Round 9
// 2255.207 us; speedup vs baseline: 1.6085x; 1.3436x over previous
//
#include <hip/hip_runtime.h>
#include <hip/hip_cooperative_groups.h>
#include <cmath>

typedef __bf16 bf16x8 __attribute__((ext_vector_type(8)));
typedef float floatx4 __attribute__((ext_vector_type(4)));
typedef unsigned ux4 __attribute__((ext_vector_type(4)));
typedef unsigned short u16;

#define B_ 16
#define T_ 512
#define D_ 512
#define H_ 1024
#define G_ 2048  // 2H
#define BH (B_ * H_)
#define HP 1032  // lds h row pitch in u16 (+8 elems breaks power-of-2 bank stride)

#define AS_BF16X8(x) (*reinterpret_cast<const bf16x8*>(&(x)))

// ---------------- cast fp32 -> bf16 (RNE) ----------------
__global__ void cast_f32_bf16(const float* __restrict__ src, u16* __restrict__ dst, int n) {
  int i = blockIdx.x * blockDim.x + threadIdx.x;
  int stride = gridDim.x * blockDim.x;
  for (; i < n; i += stride) {
    __bf16 b = (__bf16)src[i];
    dst[i] = *reinterpret_cast<u16*>(&b);
  }
}

// ---------------- w = x @ W^T  (bf16 MFMA, fp32 out), layout w[t][b][2H] ----------------
__launch_bounds__(256, 1)
__global__ void gemm_xW(const u16* __restrict__ xb, const u16* __restrict__ Wb,
                        float* __restrict__ w) {
  const int lane = threadIdx.x & 63;
  const int wv = threadIdx.x >> 6;
  const int rt0 = blockIdx.x * 16;
  const int bidx = rt0 >> 9;
  const int t0 = rt0 & 511;
  const int am = lane & 15;
  const int kq = lane >> 4;

  bf16x8 af[16];
  {
    const u16* xrow = xb + (size_t)(rt0 + am) * D_ + kq * 8;
#pragma unroll
    for (int kk = 0; kk < 16; ++kk)
      af[kk] = *reinterpret_cast<const bf16x8*>(xrow + kk * 32);
  }

#pragma unroll 1
  for (int nt = 0; nt < 32; ++nt) {
    const int n0 = wv * 512 + nt * 16;
    floatx4 acc = {0.f, 0.f, 0.f, 0.f};
    const u16* wrow = Wb + (size_t)(n0 + am) * D_ + kq * 8;
#pragma unroll
    for (int kk = 0; kk < 16; ++kk) {
      bf16x8 bfr = *reinterpret_cast<const bf16x8*>(wrow + kk * 32);
      acc = __builtin_amdgcn_mfma_f32_16x16x32_bf16(af[kk], bfr, acc, 0, 0, 0);
    }
#pragma unroll
    for (int i = 0; i < 4; ++i) {
      int m = kq * 4 + i;
      w[(size_t)((t0 + m) * 16 + bidx) * G_ + n0 + am] = acc[i];
    }
  }
}

// ---------------- in-place LayerNorm over rows of 2048 ----------------
__launch_bounds__(256, 1)
__global__ void layernorm_rows(float* __restrict__ w, const float* __restrict__ gamma,
                               const float* __restrict__ beta) {
  float* r = w + (size_t)blockIdx.x * G_;
  float v[8];
  float s = 0.f, ss = 0.f;
#pragma unroll
  for (int i = 0; i < 8; ++i) {
    v[i] = r[threadIdx.x + i * 256];
    s += v[i];
    ss += v[i] * v[i];
  }
#pragma unroll
  for (int d = 1; d < 64; d <<= 1) {
    s += __shfl_xor(s, d, 64);
    ss += __shfl_xor(ss, d, 64);
  }
  __shared__ float ls[4], lss[4];
  const int wv = threadIdx.x >> 6;
  if ((threadIdx.x & 63) == 0) { ls[wv] = s; lss[wv] = ss; }
  __syncthreads();
  float S = ls[0] + ls[1] + ls[2] + ls[3];
  float SS = lss[0] + lss[1] + lss[2] + lss[3];
  float mu = S * (1.f / 2048.f);
  float var = SS * (1.f / 2048.f) - mu * mu;
  float rs = rsqrtf(var + 1e-5f);
#pragma unroll
  for (int i = 0; i < 8; ++i) {
    int g = threadIdx.x + i * 256;
    r[g] = (v[i] - mu) * rs * gamma[g] + beta[g];
  }
}

// ---------------- persistent LiGRU scan: tagged-word MALL dataflow ----------------
// 32 blocks x 512 thr. Block blk owns h cols [blk*32, +32).
// h word = (bf16<<16) | (t+1), moved ONLY via sc0 sc1 bypass ops (MALL-coherent,
// validated R8). Producer: tagged store + vmcnt(0) per thread — no flag, no
// publish barrier. Consumer: speculative 8x dwordx4 bundle (its staging share),
// per-chunk tag check, retry stale chunks. Poll and data load are the same access:
// ~2 MALL RTs per step on the critical path.
__launch_bounds__(512, 2)
__global__ void ligru_scan(const float* __restrict__ w, const u16* __restrict__ Ub,
                           const float* __restrict__ h0, float* __restrict__ out,
                           unsigned* __restrict__ hbuf) {
  const int tid = threadIdx.x;
  const int lane = tid & 63;
  const int wv = tid >> 6;
  const int am = lane & 15;
  const int kq = lane >> 4;
  const int blk = blockIdx.x;
  const int j0 = blk * 32;
  const int jt = wv >> 1;   // tile 0..3
  const int kh = wv & 1;    // K half

  __shared__ u16 lds_h[16 * HP];         // unpacked h_prev (bf16 bits)
  __shared__ float lds_r[4][2][16][16];  // [tile][K-half][batch][B-col] partials

  const int grow = (am < 8) ? (j0 + 8 * jt + am) : (H_ + j0 + 8 * jt + (am - 8));

  // U fragments: 16 rows x K=512, register resident (64 VGPR); plain cached loads
  bf16x8 uf[16];
  {
    const u16* urow = Ub + (size_t)grow * H_ + kh * 512 + kq * 8;
#pragma unroll
    for (int kk = 0; kk < 16; ++kk)
      uf[kk] = *reinterpret_cast<const bf16x8*>(urow + kk * 32);
  }

  // per-thread h ownership: batch ub, col jj
  const int ub = tid >> 5;
  const int jj = tid & 31;
  const int col = j0 + jj;
  float hreg = h0[col];
  float wa = w[(size_t)ub * G_ + col];
  float wz = w[(size_t)ub * G_ + H_ + col];

  // staging share: chunk c = 4 dwords at d0 = c*2048 + 4*tid  (batch 2c+(tid>=256))
  const int scol = 4 * (tid & 255);
  const int sb = tid >> 8;

  // publish h_0 (tag 1) for owned word; per-thread drain, no barrier
  {
    __bf16 hb = (__bf16)hreg;
    unsigned pk = ((unsigned)*reinterpret_cast<u16*>(&hb) << 16) | 1u;
    unsigned* pp = hbuf + ub * H_ + col;
    asm volatile("global_store_dword %0, %1, off sc0 sc1\n\ts_waitcnt vmcnt(0)"
                 :: "v"(pp), "v"(pk) : "memory");
  }

  for (int t = 0; t < T_; ++t) {
    const unsigned* cur = hbuf + (t & 1) * BH;
    unsigned* nxt = hbuf + ((t + 1) & 1) * BH;
    const unsigned tag = (unsigned)(t + 1);

    // ---- speculative tagged bundle: 8 chunks x dwordx4, one vmcnt ----
    ux4 chv[8];
    {
      const unsigned* a0 = cur + 0 * 2048 + 4 * tid;
      const unsigned* a1 = cur + 1 * 2048 + 4 * tid;
      const unsigned* a2 = cur + 2 * 2048 + 4 * tid;
      const unsigned* a3 = cur + 3 * 2048 + 4 * tid;
      const unsigned* a4 = cur + 4 * 2048 + 4 * tid;
      const unsigned* a5 = cur + 5 * 2048 + 4 * tid;
      const unsigned* a6 = cur + 6 * 2048 + 4 * tid;
      const unsigned* a7 = cur + 7 * 2048 + 4 * tid;
      asm volatile(
          "global_load_dwordx4 %0, %8, off sc0 sc1\n\t"
          "global_load_dwordx4 %1, %9, off sc0 sc1\n\t"
          "global_load_dwordx4 %2, %10, off sc0 sc1\n\t"
          "global_load_dwordx4 %3, %11, off sc0 sc1\n\t"
          "global_load_dwordx4 %4, %12, off sc0 sc1\n\t"
          "global_load_dwordx4 %5, %13, off sc0 sc1\n\t"
          "global_load_dwordx4 %6, %14, off sc0 sc1\n\t"
          "global_load_dwordx4 %7, %15, off sc0 sc1\n\t"
          "s_waitcnt vmcnt(0)"
          : "=&v"(chv[0]), "=&v"(chv[1]), "=&v"(chv[2]), "=&v"(chv[3]),
            "=&v"(chv[4]), "=&v"(chv[5]), "=&v"(chv[6]), "=&v"(chv[7])
          : "v"(a0), "v"(a1), "v"(a2), "v"(a3), "v"(a4), "v"(a5), "v"(a6), "v"(a7)
          : "memory");
    }

    // ---- tag check + retry stale chunks only ----
    unsigned mask = 0;
#pragma unroll
    for (int c = 0; c < 8; ++c) {
      unsigned bad = ((chv[c].x ^ tag) | (chv[c].y ^ tag) |
                      (chv[c].z ^ tag) | (chv[c].w ^ tag)) & 0xFFFFu;
      if (bad) mask |= (1u << c);
    }
    {
      unsigned rounds = 0;
      while (mask) {
        if (++rounds > (1u << 16)) break;  // valve: wrong > hung
#pragma unroll
        for (int c = 0; c < 8; ++c)
          if (mask & (1u << c)) {
            ux4 q;
            const unsigned* ac = cur + c * 2048 + 4 * tid;
            asm volatile("global_load_dwordx4 %0, %1, off sc0 sc1\n\ts_waitcnt vmcnt(0)"
                         : "=&v"(q) : "v"(ac) : "memory");
            unsigned bad = ((q.x ^ tag) | (q.y ^ tag) | (q.z ^ tag) | (q.w ^ tag)) & 0xFFFFu;
            if (!bad) { chv[c] = q; mask &= ~(1u << c); }
          }
      }
    }

    // ---- unpack to LDS: 4 tagged dwords -> 4 bf16 (one b64 write per chunk) ----
#pragma unroll
    for (int c = 0; c < 8; ++c) {
      int b = 2 * c + sb;
      unsigned lo = (chv[c].x >> 16) | (chv[c].y & 0xFFFF0000u);
      unsigned hi = (chv[c].z >> 16) | (chv[c].w & 0xFFFF0000u);
      uint2 pk; pk.x = lo; pk.y = hi;
      *reinterpret_cast<uint2*>(&lds_h[b * HP + scol]) = pk;
    }
    __syncthreads();  // (A) staging complete

    // ---- gates: D[m=batch][n=tile col] over this wave's K half ----
    floatx4 acc0 = {0, 0, 0, 0}, acc1 = {0, 0, 0, 0};
    {
      const u16* hb = &lds_h[am * HP + kh * 512 + kq * 8];
#pragma unroll
      for (int kk = 0; kk < 8; ++kk) {
        bf16x8 x0 = *reinterpret_cast<const bf16x8*>(hb + (kk + 0) * 32);
        bf16x8 x1 = *reinterpret_cast<const bf16x8*>(hb + (kk + 8) * 32);
        acc0 = __builtin_amdgcn_mfma_f32_16x16x32_bf16(x0, uf[kk + 0], acc0, 0, 0, 0);
        acc1 = __builtin_amdgcn_mfma_f32_16x16x32_bf16(x1, uf[kk + 8], acc1, 0, 0, 0);
      }
    }
    floatx4 acc = acc0 + acc1;

    // w prefetch for t+1 (plain cached loads, read-only)
    float wan, wzn;
    {
      int tn = (t + 1 < T_) ? (t + 1) : t;
      const float* wt = w + (size_t)(tn * 16 + ub) * G_;
      wan = wt[col];
      wzn = wt[H_ + col];
    }

    // park partial gates for cross-wave reduce
#pragma unroll
    for (int i = 0; i < 4; ++i)
      lds_r[jt][kh][kq * 4 + i][am] = acc[i];
    __syncthreads();  // (B) partials complete

    // ---- update: combine K-halves, pair a/z, publish tagged word ----
    float hn;
    {
      const int tl = jj >> 3, c = jj & 7;
      float a = lds_r[tl][0][ub][c] + lds_r[tl][1][ub][c] + wa;
      float z = lds_r[tl][0][ub][8 + c] + lds_r[tl][1][ub][8 + c] + wz;
      float zs = 1.f / (1.f + __expf(-z));
      hn = zs * hreg + (1.f - zs) * fmaxf(a, 0.f);
      hreg = hn;
      __bf16 hb16 = (__bf16)hn;
      unsigned pk = ((unsigned)*reinterpret_cast<u16*>(&hb16) << 16) | (tag + 1u);
      unsigned* pp = nxt + ub * H_ + col;
      asm volatile("global_store_dword %0, %1, off sc0 sc1\n\ts_waitcnt vmcnt(0)"
                   :: "v"(pp), "v"(pk) : "memory");
    }

    // out store off the critical path (plain nontemporal)
    __builtin_nontemporal_store(hn, &out[((size_t)ub * T_ + t) * H_ + col]);

    wa = wan; wz = wzn;
  }
}

// ---------------- host ----------------
extern "C" void kernel_launch(void* const* d_in, const int* in_sizes, int n_in,
                              void* d_out, int out_size, void* d_ws, size_t ws_size,
                              hipStream_t stream) {
  (void)in_sizes; (void)n_in; (void)out_size; (void)ws_size;
  const float* x = (const float*)d_in[0];
  const float* Ww = (const float*)d_in[1];
  const float* Uw = (const float*)d_in[2];
  const float* gamma = (const float*)d_in[3];
  const float* beta = (const float*)d_in[4];
  const float* h0 = (const float*)d_in[5];
  float* out = (float*)d_out;

  char* p = (char*)d_ws;
  u16* xb = (u16*)p;      p += (size_t)8192 * 512 * 2;   // 8 MB
  u16* Wb = (u16*)p;      p += (size_t)2048 * 512 * 2;   // 2 MB
  u16* Ub = (u16*)p;      p += (size_t)2048 * 1024 * 2;  // 4 MB
  float* w = (float*)p;   p += (size_t)8192 * 2048 * 4;  // 64 MB  [T][B][G]
  unsigned* hbuf = (unsigned*)p; p += (size_t)2 * BH * 4; // 128 KB tagged dwords

  hipMemsetAsync(hbuf, 0, (size_t)2 * BH * 4, stream);  // tag 0 != any real tag
  cast_f32_bf16<<<512, 256, 0, stream>>>(x, xb, 8192 * 512);
  cast_f32_bf16<<<256, 256, 0, stream>>>(Ww, Wb, 2048 * 512);
  cast_f32_bf16<<<256, 256, 0, stream>>>(Uw, Ub, 2048 * 1024);
  gemm_xW<<<512, 256, 0, stream>>>(xb, Wb, w);
  layernorm_rows<<<8192, 256, 0, stream>>>(w, gamma, beta);

  const float* wc = w;
  const u16* Ubc = Ub;
  void* args[5] = { (void*)&wc, (void*)&Ubc, (void*)&h0, (void*)&out, (void*)&hbuf };
  hipLaunchCooperativeKernel((void*)ligru_scan, dim3(32), dim3(512), args, 0, stream);
}

// Round 10
// 1894.527 us; speedup vs baseline: 1.9147x; 1.1904x over previous
//
#include <hip/hip_runtime.h>
#include <hip/hip_cooperative_groups.h>
#include <cmath>

typedef __bf16 bf16x8 __attribute__((ext_vector_type(8)));
typedef float floatx4 __attribute__((ext_vector_type(4)));
typedef unsigned ux4 __attribute__((ext_vector_type(4)));
typedef unsigned short u16;

#define B_ 16
#define T_ 512
#define D_ 512
#define H_ 1024
#define G_ 2048  // 2H
#define BH (B_ * H_)
#define HP 1032  // lds h row pitch in u16 (+8 elems breaks power-of-2 bank stride)

// ---------------- cast fp32 -> bf16 (RNE) ----------------
__global__ void cast_f32_bf16(const float* __restrict__ src, u16* __restrict__ dst, int n) {
  int i = blockIdx.x * blockDim.x + threadIdx.x;
  int stride = gridDim.x * blockDim.x;
  for (; i < n; i += stride) {
    __bf16 b = (__bf16)src[i];
    dst[i] = *reinterpret_cast<u16*>(&b);
  }
}

// ---------------- w = x @ W^T  (bf16 MFMA, fp32 out), layout w[t][b][2H] ----------------
__launch_bounds__(256, 1)
__global__ void gemm_xW(const u16* __restrict__ xb, const u16* __restrict__ Wb,
                        float* __restrict__ w) {
  const int lane = threadIdx.x & 63;
  const int wv = threadIdx.x >> 6;
  const int rt0 = blockIdx.x * 16;
  const int bidx = rt0 >> 9;
  const int t0 = rt0 & 511;
  const int am = lane & 15;
  const int kq = lane >> 4;

  bf16x8 af[16];
  {
    const u16* xrow = xb + (size_t)(rt0 + am) * D_ + kq * 8;
#pragma unroll
    for (int kk = 0; kk < 16; ++kk)
      af[kk] = *reinterpret_cast<const bf16x8*>(xrow + kk * 32);
  }

#pragma unroll 1
  for (int nt = 0; nt < 32; ++nt) {
    const int n0 = wv * 512 + nt * 16;
    floatx4 acc = {0.f, 0.f, 0.f, 0.f};
    const u16* wrow = Wb + (size_t)(n0 + am) * D_ + kq * 8;
#pragma unroll
    for (int kk = 0; kk < 16; ++kk) {
      bf16x8 bfr = *reinterpret_cast<const bf16x8*>(wrow + kk * 32);
      acc = __builtin_amdgcn_mfma_f32_16x16x32_bf16(af[kk], bfr, acc, 0, 0, 0);
    }
#pragma unroll
    for (int i = 0; i < 4; ++i) {
      int m = kq * 4 + i;
      w[(size_t)((t0 + m) * 16 + bidx) * G_ + n0 + am] = acc[i];
    }
  }
}

// ---------------- in-place LayerNorm over rows of 2048 ----------------
__launch_bounds__(256, 1)
__global__ void layernorm_rows(float* __restrict__ w, const float* __restrict__ gamma,
                               const float* __restrict__ beta) {
  float* r = w + (size_t)blockIdx.x * G_;
  float v[8];
  float s = 0.f, ss = 0.f;
#pragma unroll
  for (int i = 0; i < 8; ++i) {
    v[i] = r[threadIdx.x + i * 256];
    s += v[i];
    ss += v[i] * v[i];
  }
#pragma unroll
  for (int d = 1; d < 64; d <<= 1) {
    s += __shfl_xor(s, d, 64);
    ss += __shfl_xor(ss, d, 64);
  }
  __shared__ float ls[4], lss[4];
  const int wv = threadIdx.x >> 6;
  if ((threadIdx.x & 63) == 0) { ls[wv] = s; lss[wv] = ss; }
  __syncthreads();
  float S = ls[0] + ls[1] + ls[2] + ls[3];
  float SS = lss[0] + lss[1] + lss[2] + lss[3];
  float mu = S * (1.f / 2048.f);
  float var = SS * (1.f / 2048.f) - mu * mu;
  float rs = rsqrtf(var + 1e-5f);
#pragma unroll
  for (int i = 0; i < 8; ++i) {
    int g = threadIdx.x + i * 256;
    r[g] = (v[i] - mu) * rs * gamma[g] + beta[g];
  }
}

// ---------------- persistent LiGRU scan: tagged-word MALL dataflow ----------------
// 32 blocks x 512 thr. Block blk owns h cols [blk*32, +32).
// h word = (bf16<<16) | (t+1), moved ONLY via sc0 sc1 bypass ops (MALL-coherent,
// validated R8/R9). Producer: tagged store, fire-and-forget (no vmcnt stall).
// Consumer: 8x dwordx4 bundle (one vmcnt), tag check, BATCHED retry: whole
// bundle re-issued per round, so a round costs ~1 MALL RT, not 8 serial RTs.
__launch_bounds__(512, 2)
__global__ void ligru_scan(const float* __restrict__ w, const u16* __restrict__ Ub,
                           const float* __restrict__ h0, float* __restrict__ out,
                           unsigned* __restrict__ hbuf) {
  const int tid = threadIdx.x;
  const int lane = tid & 63;
  const int wv = tid >> 6;
  const int am = lane & 15;
  const int kq = lane >> 4;
  const int blk = blockIdx.x;
  const int j0 = blk * 32;
  const int jt = wv >> 1;   // tile 0..3
  const int kh = wv & 1;    // K half

  __shared__ u16 lds_h[16 * HP];         // unpacked h_prev (bf16 bits)
  __shared__ float lds_r[4][2][16][16];  // [tile][K-half][batch][B-col] partials

  const int grow = (am < 8) ? (j0 + 8 * jt + am) : (H_ + j0 + 8 * jt + (am - 8));

  // U fragments: 16 rows x K=512, register resident (64 VGPR); plain cached loads
  bf16x8 uf[16];
  {
    const u16* urow = Ub + (size_t)grow * H_ + kh * 512 + kq * 8;
#pragma unroll
    for (int kk = 0; kk < 16; ++kk)
      uf[kk] = *reinterpret_cast<const bf16x8*>(urow + kk * 32);
  }

  // per-thread h ownership: batch ub, col jj
  const int ub = tid >> 5;
  const int jj = tid & 31;
  const int col = j0 + jj;
  float hreg = h0[col];
  float wa = w[(size_t)ub * G_ + col];
  float wz = w[(size_t)ub * G_ + H_ + col];

  // staging share: chunk c = 4 dwords at c*2048 + 4*tid (batch 2c+(tid>=256))
  const int scol = 4 * (tid & 255);
  const int sb = tid >> 8;

  // publish h_0 (tag 1) for owned word; fire-and-forget
  {
    __bf16 hb = (__bf16)hreg;
    unsigned pk = ((unsigned)*reinterpret_cast<u16*>(&hb) << 16) | 1u;
    unsigned* pp = hbuf + ub * H_ + col;
    asm volatile("global_store_dword %0, %1, off sc0 sc1"
                 :: "v"(pp), "v"(pk) : "memory");
  }

  for (int t = 0; t < T_; ++t) {
    const unsigned* cur = hbuf + (t & 1) * BH;
    unsigned* nxt = hbuf + ((t + 1) & 1) * BH;
    const unsigned tag = (unsigned)(t + 1);

    // ---- tagged bundle, BATCHED retry: all 8 chunks in flight per round ----
    ux4 chv[8];
    {
      const unsigned* a0 = cur + 0 * 2048 + 4 * tid;
      const unsigned* a1 = cur + 1 * 2048 + 4 * tid;
      const unsigned* a2 = cur + 2 * 2048 + 4 * tid;
      const unsigned* a3 = cur + 3 * 2048 + 4 * tid;
      const unsigned* a4 = cur + 4 * 2048 + 4 * tid;
      const unsigned* a5 = cur + 5 * 2048 + 4 * tid;
      const unsigned* a6 = cur + 6 * 2048 + 4 * tid;
      const unsigned* a7 = cur + 7 * 2048 + 4 * tid;
      unsigned rounds = 0;
      for (;;) {
        asm volatile(
            "global_load_dwordx4 %0, %8, off sc0 sc1\n\t"
            "global_load_dwordx4 %1, %9, off sc0 sc1\n\t"
            "global_load_dwordx4 %2, %10, off sc0 sc1\n\t"
            "global_load_dwordx4 %3, %11, off sc0 sc1\n\t"
            "global_load_dwordx4 %4, %12, off sc0 sc1\n\t"
            "global_load_dwordx4 %5, %13, off sc0 sc1\n\t"
            "global_load_dwordx4 %6, %14, off sc0 sc1\n\t"
            "global_load_dwordx4 %7, %15, off sc0 sc1\n\t"
            "s_waitcnt vmcnt(0)"
            : "=&v"(chv[0]), "=&v"(chv[1]), "=&v"(chv[2]), "=&v"(chv[3]),
              "=&v"(chv[4]), "=&v"(chv[5]), "=&v"(chv[6]), "=&v"(chv[7])
            : "v"(a0), "v"(a1), "v"(a2), "v"(a3), "v"(a4), "v"(a5), "v"(a6), "v"(a7)
            : "memory");
        unsigned bad = 0;
#pragma unroll
        for (int c = 0; c < 8; ++c)
          bad |= ((chv[c].x ^ tag) | (chv[c].y ^ tag) |
                  (chv[c].z ^ tag) | (chv[c].w ^ tag)) & 0xFFFFu;
        if (!bad) break;
        if (++rounds > (1u << 11)) break;  // valve: wrong > hung
      }
    }

    // ---- unpack to LDS: 4 tagged dwords -> 4 bf16 (one b64 write per chunk) ----
#pragma unroll
    for (int c = 0; c < 8; ++c) {
      int b = 2 * c + sb;
      unsigned lo = (chv[c].x >> 16) | (chv[c].y & 0xFFFF0000u);
      unsigned hi = (chv[c].z >> 16) | (chv[c].w & 0xFFFF0000u);
      uint2 pk; pk.x = lo; pk.y = hi;
      *reinterpret_cast<uint2*>(&lds_h[b * HP + scol]) = pk;
    }
    __syncthreads();  // (A) staging complete

    // ---- gates: D[m=batch][n=tile col] over this wave's K half ----
    floatx4 acc0 = {0, 0, 0, 0}, acc1 = {0, 0, 0, 0};
    {
      const u16* hb = &lds_h[am * HP + kh * 512 + kq * 8];
#pragma unroll
      for (int kk = 0; kk < 8; ++kk) {
        bf16x8 x0 = *reinterpret_cast<const bf16x8*>(hb + (kk + 0) * 32);
        bf16x8 x1 = *reinterpret_cast<const bf16x8*>(hb + (kk + 8) * 32);
        acc0 = __builtin_amdgcn_mfma_f32_16x16x32_bf16(x0, uf[kk + 0], acc0, 0, 0, 0);
        acc1 = __builtin_amdgcn_mfma_f32_16x16x32_bf16(x1, uf[kk + 8], acc1, 0, 0, 0);
      }
    }
    floatx4 acc = acc0 + acc1;

    // w prefetch for t+1 (plain cached loads, read-only)
    float wan, wzn;
    {
      int tn = (t + 1 < T_) ? (t + 1) : t;
      const float* wt = w + (size_t)(tn * 16 + ub) * G_;
      wan = wt[col];
      wzn = wt[H_ + col];
    }

    // park partial gates for cross-wave reduce
#pragma unroll
    for (int i = 0; i < 4; ++i)
      lds_r[jt][kh][kq * 4 + i][am] = acc[i];
    __syncthreads();  // (B) partials complete

    // ---- update: combine K-halves, pair a/z, publish tagged word ----
    float hn;
    {
      const int tl = jj >> 3, c = jj & 7;
      float a = lds_r[tl][0][ub][c] + lds_r[tl][1][ub][c] + wa;
      float z = lds_r[tl][0][ub][8 + c] + lds_r[tl][1][ub][8 + c] + wz;
      float zs = 1.f / (1.f + __expf(-z));
      hn = zs * hreg + (1.f - zs) * fmaxf(a, 0.f);
      hreg = hn;
      __bf16 hb16 = (__bf16)hn;
      unsigned pk = ((unsigned)*reinterpret_cast<u16*>(&hb16) << 16) | (tag + 1u);
      unsigned* pp = nxt + ub * H_ + col;
      asm volatile("global_store_dword %0, %1, off sc0 sc1"
                   :: "v"(pp), "v"(pk) : "memory");
    }

    // out store off the critical path (plain nontemporal)
    __builtin_nontemporal_store(hn, &out[((size_t)ub * T_ + t) * H_ + col]);

    wa = wan; wz = wzn;
  }
}

// ---------------- host ----------------
extern "C" void kernel_launch(void* const* d_in, const int* in_sizes, int n_in,
                              void* d_out, int out_size, void* d_ws, size_t ws_size,
                              hipStream_t stream) {
  (void)in_sizes; (void)n_in; (void)out_size; (void)ws_size;
  const float* x = (const float*)d_in[0];
  const float* Ww = (const float*)d_in[1];
  const float* Uw = (const float*)d_in[2];
  const float* gamma = (const float*)d_in[3];
  const float* beta = (const float*)d_in[4];
  const float* h0 = (const float*)d_in[5];
  float* out = (float*)d_out;

  char* p = (char*)d_ws;
  u16* xb = (u16*)p;      p += (size_t)8192 * 512 * 2;   // 8 MB
  u16* Wb = (u16*)p;      p += (size_t)2048 * 512 * 2;   // 2 MB
  u16* Ub = (u16*)p;      p += (size_t)2048 * 1024 * 2;  // 4 MB
  float* w = (float*)p;   p += (size_t)8192 * 2048 * 4;  // 64 MB  [T][B][G]
  unsigned* hbuf = (unsigned*)p; p += (size_t)2 * BH * 4; // 128 KB tagged dwords

  hipMemsetAsync(hbuf, 0, (size_t)2 * BH * 4, stream);  // tag 0 != any real tag
  cast_f32_bf16<<<512, 256, 0, stream>>>(x, xb, 8192 * 512);
  cast_f32_bf16<<<256, 256, 0, stream>>>(Ww, Wb, 2048 * 512);
  cast_f32_bf16<<<256, 256, 0, stream>>>(Uw, Ub, 2048 * 1024);
  gemm_xW<<<512, 256, 0, stream>>>(xb, Wb, w);
  layernorm_rows<<<8192, 256, 0, stream>>>(w, gamma, beta);

  const float* wc = w;
  const u16* Ubc = Ub;
  void* args[5] = { (void*)&wc, (void*)&Ubc, (void*)&h0, (void*)&out, (void*)&hbuf };
  hipLaunchCooperativeKernel((void*)ligru_scan, dim3(32), dim3(512), args, 0, stream);
}